// Round 1
// baseline (118.786 us; speedup 1.0000x reference)
//
#include <hip/hip_runtime.h>

#define DIM 512
#define NROWS 65536

// One wave per row (grid-strided). Lane l covers floats [l*4, l*4+4) and
// [256 + l*4, ...): 64 lanes x 2 x float4 = 512 floats = one full row,
// coalesced 1 KiB per vector load instruction.
__global__ __launch_bounds__(256) void nn_dist_kernel(
    const float* __restrict__ x,
    const float* __restrict__ ctx,
    unsigned long long* __restrict__ best) {
  const int lane = threadIdx.x & 63;
  const int wave_global = (blockIdx.x << 2) | (threadIdx.x >> 6);
  const int n_waves = gridDim.x << 2;

  const float4 xa = *reinterpret_cast<const float4*>(x + lane * 4);
  const float4 xb = *reinterpret_cast<const float4*>(x + 256 + lane * 4);

  float best_d = 3.402823466e38f;
  int best_i = 0;

  for (int row = wave_global; row < NROWS; row += n_waves) {
    const float* r = ctx + (size_t)row * DIM;
    const float4 ca = *reinterpret_cast<const float4*>(r + lane * 4);
    const float4 cb = *reinterpret_cast<const float4*>(r + 256 + lane * 4);
    float s = 0.f, d;
    d = ca.x - xa.x; s = fmaf(d, d, s);
    d = ca.y - xa.y; s = fmaf(d, d, s);
    d = ca.z - xa.z; s = fmaf(d, d, s);
    d = ca.w - xa.w; s = fmaf(d, d, s);
    d = cb.x - xb.x; s = fmaf(d, d, s);
    d = cb.y - xb.y; s = fmaf(d, d, s);
    d = cb.z - xb.z; s = fmaf(d, d, s);
    d = cb.w - xb.w; s = fmaf(d, d, s);
    // wave-wide sum (64 lanes)
    #pragma unroll
    for (int off = 32; off; off >>= 1) s += __shfl_xor(s, off, 64);
    if (s < best_d) { best_d = s; best_i = row; }
  }

  if (lane == 0) {
    // dist >= 0 -> IEEE bit pattern is order-preserving; index in low bits
    // gives "first index wins" on exact ties, matching jnp.argmin.
    unsigned long long packed =
        ((unsigned long long)__float_as_uint(best_d) << 32) | (unsigned)best_i;
    atomicMin(best, packed);
  }
}

__global__ __launch_bounds__(128) void nn_copy_kernel(
    const float* __restrict__ ctx,
    const unsigned long long* __restrict__ best,
    float* __restrict__ out) {
  const int idx = (int)(unsigned)(*best & 0xFFFFFFFFull);
  const int t = threadIdx.x;  // 128 threads x float4 = 512 floats
  reinterpret_cast<float4*>(out)[t] =
      reinterpret_cast<const float4*>(ctx + (size_t)idx * DIM)[t];
}

extern "C" void kernel_launch(void* const* d_in, const int* in_sizes, int n_in,
                              void* d_out, int out_size, void* d_ws, size_t ws_size,
                              hipStream_t stream) {
  const float* x = (const float*)d_in[0];
  const float* ctx = (const float*)d_in[1];
  float* out = (float*)d_out;
  unsigned long long* best = (unsigned long long*)d_ws;

  // d_ws is poisoned 0xAA by the harness; set sentinel to all-ones (max u64).
  hipMemsetAsync(d_ws, 0xFF, sizeof(unsigned long long), stream);

  nn_dist_kernel<<<2048, 256, 0, stream>>>(x, ctx, best);
  nn_copy_kernel<<<1, 128, 0, stream>>>(ctx, best, out);
}

// Round 2
// 27.356 us; speedup vs baseline: 4.3423x; 4.3423x over previous
//
#include <hip/hip_runtime.h>

#define DIM 512
#define NROWS 65536
#define NBLOCKS 2048   // 4 waves/block -> 8192 waves; 4 rows/wave/iter -> 2 iters

// One wave computes 4 rows per iteration. Lane l covers floats [l*4, l*4+4)
// and [256 + l*4, ...) of each row: fully coalesced dwordx4, 8 loads in
// flight per wave per iteration (8 KiB). No global atomics: per-block best
// goes to d_ws via a plain store.
__global__ __launch_bounds__(256) void nn_dist_kernel(
    const float* __restrict__ x,
    const float* __restrict__ ctx,
    unsigned long long* __restrict__ block_best) {
  const int lane = threadIdx.x & 63;
  const int wave_in_block = threadIdx.x >> 6;
  const int wave_global = (blockIdx.x << 2) | wave_in_block;
  const int n_waves = NBLOCKS << 2;  // 8192

  const float4 xa = *reinterpret_cast<const float4*>(x + lane * 4);
  const float4 xb = *reinterpret_cast<const float4*>(x + 256 + lane * 4);

  float best_d = 3.402823466e38f;
  int best_i = 0;

  for (int base = wave_global * 4; base < NROWS; base += n_waves * 4) {
    const float* r = ctx + (size_t)base * DIM + lane * 4;
    float4 ca[4], cb[4];
#pragma unroll
    for (int j = 0; j < 4; ++j) {
      ca[j] = *reinterpret_cast<const float4*>(r + j * DIM);
      cb[j] = *reinterpret_cast<const float4*>(r + j * DIM + 256);
    }
    float s[4];
#pragma unroll
    for (int j = 0; j < 4; ++j) {
      float t = 0.f, d;
      d = ca[j].x - xa.x; t = fmaf(d, d, t);
      d = ca[j].y - xa.y; t = fmaf(d, d, t);
      d = ca[j].z - xa.z; t = fmaf(d, d, t);
      d = ca[j].w - xa.w; t = fmaf(d, d, t);
      d = cb[j].x - xb.x; t = fmaf(d, d, t);
      d = cb[j].y - xb.y; t = fmaf(d, d, t);
      d = cb[j].z - xb.z; t = fmaf(d, d, t);
      d = cb[j].w - xb.w; t = fmaf(d, d, t);
      s[j] = t;
    }
    // 4 independent wave-wide sums; the 6-step chains pipeline.
#pragma unroll
    for (int off = 32; off; off >>= 1) {
#pragma unroll
      for (int j = 0; j < 4; ++j) s[j] += __shfl_xor(s[j], off, 64);
    }
#pragma unroll
    for (int j = 0; j < 4; ++j) {
      if (s[j] < best_d) { best_d = s[j]; best_i = base + j; }  // strict < => first idx wins
    }
  }

  // Block-level reduce: 4 waves -> 1 plain store. dist >= 0 so IEEE bits are
  // order-preserving; idx in low bits => smallest idx wins exact ties.
  __shared__ unsigned long long lds[4];
  if (lane == 0) {
    lds[wave_in_block] =
        ((unsigned long long)__float_as_uint(best_d) << 32) | (unsigned)best_i;
  }
  __syncthreads();
  if (threadIdx.x == 0) {
    unsigned long long m = lds[0];
#pragma unroll
    for (int j = 1; j < 4; ++j) m = lds[j] < m ? lds[j] : m;
    block_best[blockIdx.x] = m;
  }
}

// Single block: reduce 2048 candidates, then copy the winning row.
__global__ __launch_bounds__(256) void nn_reduce_copy_kernel(
    const float* __restrict__ ctx,
    const unsigned long long* __restrict__ block_best,
    float* __restrict__ out) {
  __shared__ unsigned long long lds[4];
  __shared__ int s_idx;
  const int t = threadIdx.x;

  unsigned long long m = ~0ull;
#pragma unroll
  for (int k = 0; k < NBLOCKS / 256; ++k) {
    unsigned long long v = block_best[t + (k << 8)];
    m = v < m ? v : m;
  }
#pragma unroll
  for (int off = 32; off; off >>= 1) {
    unsigned long long o = __shfl_xor(m, off, 64);
    m = o < m ? o : m;
  }
  if ((t & 63) == 0) lds[t >> 6] = m;
  __syncthreads();
  if (t == 0) {
    unsigned long long mm = lds[0];
#pragma unroll
    for (int j = 1; j < 4; ++j) mm = lds[j] < mm ? lds[j] : mm;
    s_idx = (int)(unsigned)(mm & 0xFFFFFFFFull);
  }
  __syncthreads();

  const float* src = ctx + (size_t)s_idx * DIM;
  reinterpret_cast<float2*>(out)[t] = reinterpret_cast<const float2*>(src)[t];
}

extern "C" void kernel_launch(void* const* d_in, const int* in_sizes, int n_in,
                              void* d_out, int out_size, void* d_ws, size_t ws_size,
                              hipStream_t stream) {
  const float* x = (const float*)d_in[0];
  const float* ctx = (const float*)d_in[1];
  float* out = (float*)d_out;
  unsigned long long* block_best = (unsigned long long*)d_ws;  // 2048 * 8 B = 16 KiB

  nn_dist_kernel<<<NBLOCKS, 256, 0, stream>>>(x, ctx, block_best);
  nn_reduce_copy_kernel<<<1, 256, 0, stream>>>(ctx, block_best, out);
}